// Round 6
// baseline (87.235 us; speedup 1.0000x reference)
//
#include <hip/hip_runtime.h>

// Conv3D implicit GEMM, round 6: pre-padded bf16 x in d_ws + async
// global_load_lds staging (no VALU, no bounds logic), TH=2 tiles, balanced
// grid (1792 = 7 blocks/CU), depth-1 double-buffered A (global) and B (LDS)
// fragments. Fallback to round-5 kernel if ws_size too small.
// x (8,3,16,112,112) f32, w (64,3,5,7,7), bias (64,) -> out (8,64,16,56,56) f32

typedef __attribute__((ext_vector_type(8))) short short8;
typedef __attribute__((ext_vector_type(4))) float f32x4;

#define CI 3
#define DI 16
#define HI 112
#define WI 112
#define CO 64
#define DO_ 16
#define HO 56
#define WO 56
#define HW_IN 12544
#define DHWO 50176

#define NROW 105            // real (c,kd,kh) rows
#define NCH 27              // K chunks of 32 (105 rows of 8, padded to 108)

// xpad: bf16 [8][3][20 dpad][119 hpad][144 slots] ; slot s = win s-3, slots>=120 zero
#define XP_ROW 144          // shorts per row (288 B)
#define XP_H   119
#define XP_D   20
#define XPAD_SHORTS (8*3*XP_D*XP_H*XP_ROW)   // 8,217,216
#define XPAD_BYTES  (XPAD_SHORTS*2)          // 16,434,432
#define WBUF_OFF    XPAD_BYTES
#define WBUF_BYTES  (NCH*4*64*16)            // 110,592
#define WS_NEED     (WBUF_OFF + WBUF_BYTES + 4096)

#define SEG_SH 1536         // LDS shorts per (c,p) segment (9 rows*144 + pad to 3072B)

__device__ __forceinline__ unsigned short f2bf(float f) {
    unsigned u = __float_as_uint(f);
    return (unsigned short)((u + 0x7FFFu + ((u >> 16) & 1u)) >> 16);
}

// ---------- prep 1: x -> fully halo-padded bf16 xpad ----------
__global__ void prep_xpad(const float* __restrict__ x, unsigned* __restrict__ xp) {
    const int g = blockIdx.x * 256 + threadIdx.x;   // 4,112,640 dwords exactly
    const int dw = g % 72;
    int r = g / 72;
    const int hp = r % XP_H; r /= XP_H;
    const int dp = r % XP_D; r /= XP_D;
    const int c  = r % 3;
    const int n  = r / 3;
    const int din = dp - 2, hin = hp - 3;
    const int w0  = 2 * dw - 3;
    float v0 = 0.0f, v1 = 0.0f;
    if ((unsigned)din < (unsigned)DI && (unsigned)hin < (unsigned)HI) {
        const float* xr = x + ((n * CI + c) * DI + din) * HW_IN + hin * WI;
        if ((unsigned)w0 < (unsigned)WI)       v0 = xr[w0];
        if ((unsigned)(w0 + 1) < (unsigned)WI) v1 = xr[w0 + 1];
    }
    unsigned pk;
    asm("v_cvt_pk_bf16_f32 %0, %1, %2" : "=v"(pk) : "v"(v0), "v"(v1));
    xp[g] = pk;
}

// ---------- prep 2: weights -> fragment-ready bf16 ----------
__global__ void prep_weights(const float* __restrict__ wgt, short8* __restrict__ wbuf) {
    const int t    = blockIdx.x * 64 + threadIdx.x;   // 27*4*64 = 6912
    const int lane = t & 63;
    const int cf   = t >> 6;
    const int ch   = cf >> 2;
    const int a    = cf & 3;
    const int l15  = lane & 15;
    const int kgrp = lane >> 4;
    const int co   = a * 16 + l15;
    const int r    = ch * 4 + kgrp;
    const int rc   = (r < NROW) ? r : (NROW - 1);
    const int c    = rc / 35;
    const int kd   = (rc / 7) % 5;
    const int kh   = rc % 7;
    const float* wsrc = wgt + (((co * CI + c) * 5 + kd) * 7 + kh) * 7;
    short8 v;
    #pragma unroll
    for (int j = 0; j < 8; ++j) {
        float w = (r < NROW && j < 7) ? wsrc[j] : 0.0f;
        v[j] = (short)f2bf(w);
    }
    wbuf[(size_t)cf * 64 + lane] = v;
}

// chunk-row -> LDS short-index base: r = ch*4+kgrp (clamped to 104)
__device__ __forceinline__ int rowbase(int r) {
    const int rc  = (r > 104) ? 104 : r;
    const int c   = (rc >= 70) ? 2 : ((rc >= 35) ? 1 : 0);
    const int rem = rc - c * 35;
    const int kd  = rem / 7;
    const int kh  = rem - kd * 7;
    return (c * 6 + kd) * SEG_SH + kh * XP_ROW;
}

#define MFMA(A, B, C) __builtin_amdgcn_mfma_f32_16x16x32_bf16(A, B, C, 0, 0, 0)

__launch_bounds__(512, 4)
__global__ void conv3d_v6(const unsigned short* __restrict__ xpad,
                          const short8* __restrict__ wbuf,
                          const float* __restrict__ bias,
                          float* __restrict__ out) {
    __shared__ __align__(16) unsigned short xl[18 * SEG_SH];   // 55296 B

    const int tid = threadIdx.x;
    int b = blockIdx.x;
    const int ht  = b % 28;  b /= 28;
    const int ddp = b & 7;
    const int n   = b >> 3;
    const int ho0 = ht * 2;
    const int dd0 = ddp * 2;

    const int lane = tid & 63;
    const int wid  = tid >> 6;

    // ---- async stage: 18 (c,p) segments of 9 rows x 288B, pre-padded src ----
    {
        const size_t nb = (size_t)(n * CI) * XP_D;
        for (int s = wid; s < 18; s += 8) {
            const int c = s / 6;
            const int p = s - c * 6;
            const char* gsrc = (const char*)(xpad +
                ((nb + (size_t)c * XP_D + (dd0 + p)) * XP_H + 2 * ho0) * XP_ROW)
                + lane * 16;
            char* ldst = (char*)&xl[s * SEG_SH];
            __builtin_amdgcn_global_load_lds(
                (const __attribute__((address_space(1))) void*)(gsrc),
                (__attribute__((address_space(3))) void*)(ldst), 16, 0, 0);
            __builtin_amdgcn_global_load_lds(
                (const __attribute__((address_space(1))) void*)(gsrc + 1024),
                (__attribute__((address_space(3))) void*)(ldst + 1024), 16, 0, 0);
            __builtin_amdgcn_global_load_lds(
                (const __attribute__((address_space(1))) void*)(gsrc + 2048),
                (__attribute__((address_space(3))) void*)(ldst + 2048), 16, 0, 0);
        }
    }
    __syncthreads();   // drains vmcnt before barrier (compiler-emitted)

    // ---- wave roles: ddl x hoL x woH ; wave = 64co x 32wo (28 real) ----
    const int ddl  = wid & 1;
    const int hoL  = (wid >> 1) & 1;
    const int woH  = wid >> 2;
    const int l15  = lane & 15;
    const int kgrp = lane >> 4;
    const int woffs = ddl * SEG_SH + hoL * (2 * XP_ROW);  // shorts
    const int spdw  = woH * 28 + l15;                      // dword offset in row, f=0

    f32x4 acc[4][2];
    #pragma unroll
    for (int a = 0; a < 4; ++a) {
        f32x4 bv;
        #pragma unroll
        for (int r = 0; r < 4; ++r) bv[r] = bias[a * 16 + kgrp * 4 + r];
        acc[a][0] = bv; acc[a][1] = bv;
    }

    const short8* wbp = wbuf + lane;
    const unsigned* xlu = reinterpret_cast<const unsigned*>(xl);

    short8 Aa[4], Ab[4];
    union BxU { unsigned u[4]; short8 s; };
    BxU pa0, pa1, pb0, pb1;

    // prologue: chunk 0 -> buffers a
    #pragma unroll
    for (int a = 0; a < 4; ++a) Aa[a] = wbp[a * 64];
    {
        const unsigned* xp = xlu + ((rowbase(kgrp) + woffs) >> 1) + spdw;
        #pragma unroll
        for (int j = 0; j < 4; ++j) { pa0.u[j] = xp[j]; pa1.u[j] = xp[16 + j]; }
    }

    for (int ch = 0; ch < NCH - 1; ch += 2) {
        // prefetch ch+1 -> b
        #pragma unroll
        for (int a = 0; a < 4; ++a) Ab[a] = wbp[((ch + 1) * 4 + a) * 64];
        {
            const unsigned* xp = xlu + ((rowbase((ch + 1) * 4 + kgrp) + woffs) >> 1) + spdw;
            #pragma unroll
            for (int j = 0; j < 4; ++j) { pb0.u[j] = xp[j]; pb1.u[j] = xp[16 + j]; }
        }
        // compute ch (buffers a)
        #pragma unroll
        for (int a = 0; a < 4; ++a) {
            acc[a][0] = MFMA(Aa[a], pa0.s, acc[a][0]);
            acc[a][1] = MFMA(Aa[a], pa1.s, acc[a][1]);
        }
        // prefetch ch+2 -> a
        #pragma unroll
        for (int a = 0; a < 4; ++a) Aa[a] = wbp[((ch + 2) * 4 + a) * 64];
        {
            const unsigned* xp = xlu + ((rowbase((ch + 2) * 4 + kgrp) + woffs) >> 1) + spdw;
            #pragma unroll
            for (int j = 0; j < 4; ++j) { pa0.u[j] = xp[j]; pa1.u[j] = xp[16 + j]; }
        }
        // compute ch+1 (buffers b)
        #pragma unroll
        for (int a = 0; a < 4; ++a) {
            acc[a][0] = MFMA(Ab[a], pb0.s, acc[a][0]);
            acc[a][1] = MFMA(Ab[a], pb1.s, acc[a][1]);
        }
    }
    // tail: chunk 26 (buffers a)
    #pragma unroll
    for (int a = 0; a < 4; ++a) {
        acc[a][0] = MFMA(Aa[a], pa0.s, acc[a][0]);
        acc[a][1] = MFMA(Aa[a], pa1.s, acc[a][1]);
    }

    // ---- store (mask dead cols: f==1 && l15>=12) ----
    const int dd = dd0 + ddl;
    const int ho = ho0 + hoL;
    const size_t obase = ((((size_t)n * CO) * DO_ + dd) * HO + ho) * WO;
    #pragma unroll
    for (int f = 0; f < 2; ++f) {
        const int wo = woH * 28 + f * 16 + l15;
        if (f == 0 || l15 < 12) {
            float* op = out + obase + wo;
            #pragma unroll
            for (int a = 0; a < 4; ++a) {
                const int co = a * 16 + kgrp * 4;
                #pragma unroll
                for (int r = 0; r < 4; ++r)
                    op[(size_t)(co + r) * DHWO] = acc[a][f][r];
            }
        }
    }
}

// =================== fallback (round-5 kernel, unchanged) ===================
#define FB_LR 13
#define FB_LROWS 234
#define FB_LWS 144
#define FB_XLSZ (FB_LROWS*FB_LWS)

__launch_bounds__(512, 2)
__global__ void conv3d_mfma4(const float* __restrict__ x,
                             const short8* __restrict__ wbuf,
                             const float* __restrict__ bias,
                             float* __restrict__ out) {
    __shared__ unsigned short xl[FB_XLSZ];
    __shared__ int rowg[FB_LROWS];
    __shared__ unsigned short tabr[108];

    const int tid = threadIdx.x;
    int b = blockIdx.x;
    const int ht  = b % 14;  b /= 14;
    const int ddp = b % 8;
    const int n   = b / 8;
    const int ho0 = ht * 4;
    const int dd0 = ddp * 2;

    if (tid < FB_LROWS) {
        const int c   = tid / (6 * FB_LR);
        const int rem = tid - c * (6 * FB_LR);
        const int p   = rem / FB_LR;
        const int rl  = rem - p * FB_LR;
        const int din = dd0 - 2 + p;
        const int hin = 2 * ho0 - 3 + rl;
        const bool ok = ((unsigned)din < (unsigned)DI) && ((unsigned)hin < (unsigned)HI);
        rowg[tid] = ok ? ((n * CI + c) * DI + din) * HW_IN + hin * WI : -1;
    }
    if (tid < 108) {
        const int rc = (tid < NROW) ? tid : (NROW - 1);
        const int c  = rc / 35;
        const int kd = (rc / 7) % 5;
        const int kh = rc % 7;
        tabr[tid] = (unsigned short)(((c * 6 + kd) * FB_LR + kh) * FB_LWS);
    }
    __syncthreads();

    const int lane = tid & 63;
    const int wid  = tid >> 6;

    for (int row = wid; row < FB_LROWS; row += 8) {
        const int base = rowg[row];
        unsigned short* dst = &xl[row * FB_LWS];
        if (lane < 57) {
            float v0 = 0.0f, v1 = 0.0f;
            const int w0 = 2 * lane - 1;
            if (base >= 0) {
                if (lane >= 1)  v0 = x[base + w0];
                if (lane <= 55) v1 = x[base + w0 + 1];
            }
            unsigned pk;
            asm("v_cvt_pk_bf16_f32 %0, %1, %2" : "=v"(pk) : "v"(v0), "v"(v1));
            *reinterpret_cast<unsigned*>(&dst[2 * lane + 2]) = pk;
        } else {
            const int dw = (lane == 57) ? 0 : lane;
            *reinterpret_cast<unsigned*>(&dst[2 * dw]) = 0u;
        }
    }
    __syncthreads();

    const int ddl  = wid & 1;
    const int hoL  = wid >> 1;
    const int l15  = lane & 15;
    const int kgrp = lane >> 4;
    const int woff = ddl * (FB_LR * FB_LWS) + hoL * (2 * FB_LWS);

    f32x4 acc[4][4];
    #pragma unroll
    for (int a = 0; a < 4; ++a) {
        f32x4 bv;
        #pragma unroll
        for (int r = 0; r < 4; ++r) bv[r] = bias[a * 16 + kgrp * 4 + r];
        #pragma unroll
        for (int f = 0; f < 4; ++f) acc[a][f] = bv;
    }

    const short8* wbp = wbuf + lane;
    short8 Acur[4], Anxt[4];
    #pragma unroll
    for (int a = 0; a < 4; ++a) Acur[a] = wbp[a * 64];
    int tb = (int)tabr[kgrp] + woff;

    const unsigned* xlu = reinterpret_cast<const unsigned*>(xl);

    for (int ch = 0; ch < NCH; ++ch) {
        int tbn = 0;
        if (ch + 1 < NCH) {
            tbn = (int)tabr[(ch + 1) * 4 + kgrp] + woff;
            #pragma unroll
            for (int a = 0; a < 4; ++a) Anxt[a] = wbp[((ch + 1) * 4 + a) * 64];
        }
        const unsigned* xp = xlu + (tb >> 1) + l15;
        union { unsigned u[4]; short8 s; } bx[4];
        #pragma unroll
        for (int f = 0; f < 4; ++f) {
            const unsigned* p = xp + f * 16;
            bx[f].u[0] = p[0]; bx[f].u[1] = p[1];
            bx[f].u[2] = p[2]; bx[f].u[3] = p[3];
        }
        #pragma unroll
        for (int f = 0; f < 4; ++f) {
            acc[0][f] = MFMA(Acur[0], bx[f].s, acc[0][f]);
            acc[1][f] = MFMA(Acur[1], bx[f].s, acc[1][f]);
            acc[2][f] = MFMA(Acur[2], bx[f].s, acc[2][f]);
            acc[3][f] = MFMA(Acur[3], bx[f].s, acc[3][f]);
        }
        tb = tbn;
        #pragma unroll
        for (int a = 0; a < 4; ++a) Acur[a] = Anxt[a];
    }

    const int dd = dd0 + ddl;
    const int ho = ho0 + hoL;
    #pragma unroll
    for (int f = 0; f < 4; ++f) {
        const int wo = f * 16 + l15;
        if (f < 3 || l15 < 8) {
            float* op = out + (((size_t)(n * CO) * DO_ + dd) * HO + ho) * WO + wo;
            #pragma unroll
            for (int a = 0; a < 4; ++a) {
                const int co = a * 16 + kgrp * 4;
                #pragma unroll
                for (int r = 0; r < 4; ++r)
                    op[(size_t)(co + r) * DHWO] = acc[a][f][r];
            }
        }
    }
}

extern "C" void kernel_launch(void* const* d_in, const int* in_sizes, int n_in,
                              void* d_out, int out_size, void* d_ws, size_t ws_size,
                              hipStream_t stream) {
    const float* x    = (const float*)d_in[0];
    const float* wgt  = (const float*)d_in[1];
    const float* bias = (const float*)d_in[2];
    float* out        = (float*)d_out;

    if (ws_size >= (size_t)WS_NEED) {
        unsigned* xpad = (unsigned*)d_ws;
        short8* wbuf   = (short8*)((char*)d_ws + WBUF_OFF);
        hipLaunchKernelGGL(prep_xpad, dim3(16065, 1, 1), dim3(256, 1, 1), 0, stream,
                           x, xpad);
        hipLaunchKernelGGL(prep_weights, dim3(NCH * 4, 1, 1), dim3(64, 1, 1), 0, stream,
                           wgt, wbuf);
        // grid: 28 ho-tiles * 8 dd-pairs * 8 n = 1792 (exactly 7 blocks/CU)
        hipLaunchKernelGGL(conv3d_v6, dim3(1792, 1, 1), dim3(512, 1, 1), 0, stream,
                           (const unsigned short*)xpad, wbuf, bias, out);
    } else {
        short8* wbuf = (short8*)d_ws;
        hipLaunchKernelGGL(prep_weights, dim3(NCH * 4, 1, 1), dim3(64, 1, 1), 0, stream,
                           wgt, wbuf);
        hipLaunchKernelGGL(conv3d_mfma4, dim3(896, 1, 1), dim3(512, 1, 1), 0, stream,
                           x, wbuf, bias, out);
    }
}